// Round 8
// baseline (203.610 us; speedup 1.0000x reference)
//
#include <hip/hip_runtime.h>

#define NN 100000
#define EE 1600000
#define FIN 512
#define HID 64
#define NC 16
#define ELLW 64          // max in-degree capacity (Poisson(16), max ~42)
#define CPAD 16          // one bucket cursor per 64B line

#define KB2 391          // buckets: 256 dst nodes each, ceil(100000/256)
#define BCAP2 4608       // staged entries per bucket (mean 4082, +8 sigma)
#define S1E 2048         // edges per bin block

typedef __attribute__((ext_vector_type(8))) short bf16x8;
typedef __attribute__((ext_vector_type(4))) float f32x4;

__device__ __forceinline__ unsigned short f2bf(float f) {
    union { float f; unsigned u; } v; v.f = f;
    unsigned r = v.u + 0x7FFFu + ((v.u >> 16) & 1u);   // RNE
    return (unsigned short)(r >> 16);
}
__device__ __forceinline__ float asf(unsigned u) {
    union { unsigned u; float f; } v; v.u = u; return v.f;
}

// ---------------- init: zero bucket cursors + W1 -> bf16 transposed [col][k] ----------------
__global__ void k_init(const float* __restrict__ W1, unsigned short* __restrict__ W1t,
                       unsigned* __restrict__ gcur) {
    int id = blockIdx.x * blockDim.x + threadIdx.x;
    if (id < KB2 * CPAD) gcur[id] = 0u;
    if (id < HID * FIN) {
        int c = id >> 9;      // col 0..63
        int k = id & 511;
        W1t[id] = f2bf(W1[(size_t)k * HID + c]);
    }
}

// ---------------- bin: bucket edges by dst (256-node buckets), coalesced staged output ----------------
__global__ __launch_bounds__(256) void k_bin(
    const int* __restrict__ erow, const int* __restrict__ ecol,
    unsigned* __restrict__ gcur, unsigned* __restrict__ staged) {
    __shared__ unsigned hist[512];
    __shared__ unsigned scanb[512];
    __shared__ unsigned cur[512];
    __shared__ unsigned sbase[512];
    __shared__ unsigned pk[S1E];
    __shared__ unsigned ga[S1E];
    const int t = threadIdx.x;
    const int e0 = blockIdx.x * S1E;

    hist[t] = 0; hist[t + 256] = 0;
    cur[t] = 0;  cur[t + 256] = 0;
    __syncthreads();

    unsigned pkd[8];
    int bs[8];
#pragma unroll
    for (int i = 0; i < 8; ++i) {
        int e = e0 + i * 256 + t;
        if (e < EE) {
            int c = ecol[e];
            int src = erow[e];
            int b = c >> 8;                       // 0..390
            bs[i] = b;
            pkd[i] = (unsigned)src | ((unsigned)(c & 255) << 17);
            atomicAdd(&hist[b], 1u);
        } else {
            bs[i] = -1;
        }
    }
    __syncthreads();
    // two parallel 256-wide inclusive scans, then offset the upper half
    scanb[t] = hist[t];
    scanb[t + 256] = hist[t + 256];
    __syncthreads();
    for (int d = 1; d < 256; d <<= 1) {
        unsigned aA = (t >= d) ? scanb[t - d] : 0u;
        unsigned aB = (t >= d) ? scanb[256 + t - d] : 0u;
        __syncthreads();
        scanb[t] += aA;
        scanb[256 + t] += aB;
        __syncthreads();
    }
    unsigned totA = scanb[255];
    scanb[256 + t] += totA;
    __syncthreads();
    // reserve global ranges per bucket
    if (hist[t] > 0) sbase[t] = atomicAdd(&gcur[(size_t)t * CPAD], hist[t]);
    {
        int t2 = t + 256;
        if (t2 < KB2 && hist[t2] > 0) sbase[t2] = atomicAdd(&gcur[(size_t)t2 * CPAD], hist[t2]);
    }
    __syncthreads();
#pragma unroll
    for (int i = 0; i < 8; ++i) {
        int b = bs[i];
        if (b >= 0) {
            unsigned ls = atomicAdd(&cur[b], 1u);
            unsigned pos = scanb[b] - hist[b] + ls;
            unsigned gp = sbase[b] + ls;
            pk[pos] = pkd[i];
            ga[pos] = (gp < BCAP2) ? ((unsigned)b * BCAP2 + gp) : 0xFFFFFFFFu;
        }
    }
    __syncthreads();
    unsigned tot = scanb[511];
#pragma unroll
    for (int i = 0; i < 8; ++i) {
        unsigned idx = i * 256 + t;
        if (idx < tot && ga[idx] != 0xFFFFFFFFu) staged[ga[idx]] = pk[idx];
    }
}

// ---------------- scat2: per-bucket ELL scatter via LDS counters; emits cnt+dinv ----------------
__global__ __launch_bounds__(256) void k_scat2(
    const unsigned* __restrict__ gcur, const unsigned* __restrict__ staged,
    int* __restrict__ ell, unsigned* __restrict__ cnt, float* __restrict__ dinv) {
    __shared__ unsigned lcnt[256];
    const int t = threadIdx.x;
    const int b = blockIdx.x;
    lcnt[t] = 0;
    __syncthreads();
    unsigned n = gcur[(size_t)b * CPAD];
    if (n > BCAP2) n = BCAP2;
    const unsigned base = (unsigned)b * BCAP2;
    const int node0 = b << 8;
    for (unsigned idx = t; idx < n; idx += 256) {
        unsigned p = staged[base + idx];
        int src = (int)(p & 0x1FFFFu);
        int dl = (int)(p >> 17);
        unsigned slot = atomicAdd(&lcnt[dl], 1u);
        if (slot < ELLW) ell[(size_t)(node0 + dl) * ELLW + slot] = src;
    }
    __syncthreads();
    int node = node0 + t;
    if (node < NN) {
        unsigned c = lcnt[t];
        cnt[node] = c;
        dinv[node] = 1.0f / sqrtf((float)(c + 1u));   // +1 self-loop
    }
}

// ---------------- layer 1 GEMM via MFMA: h1s = bf16( (A@W1) * dinv ) ----------------
#define BM 128
#define BK 64

__global__ __launch_bounds__(256) void k_gemm1(
    const float* __restrict__ A, const unsigned short* __restrict__ W1t,
    const float* __restrict__ dinv, unsigned short* __restrict__ h1s) {
    __shared__ unsigned short sA[BM * BK];   // 16 KB
    __shared__ unsigned short sB[HID * BK];  // 8 KB
    const int t = threadIdx.x;
    const int w = t >> 6;
    const int l = t & 63;
    const int row0 = blockIdx.x * BM;

    f32x4 acc[2][4];
#pragma unroll
    for (int fr = 0; fr < 2; ++fr)
#pragma unroll
        for (int fc = 0; fc < 4; ++fc)
            acc[fr][fc] = (f32x4){0.f, 0.f, 0.f, 0.f};

    for (int kb = 0; kb < FIN; kb += BK) {
        __syncthreads();
#pragma unroll
        for (int i = 0; i < 4; ++i) {
            int idx = i * 256 + t;
            int r = idx >> 3, g = idx & 7;
            float4 v0 = {0.f, 0.f, 0.f, 0.f}, v1 = {0.f, 0.f, 0.f, 0.f};
            if (row0 + r < NN) {
                const float* p = &A[(size_t)(row0 + r) * FIN + kb + g * 8];
                v0 = *reinterpret_cast<const float4*>(p);
                v1 = *reinterpret_cast<const float4*>(p + 4);
            }
            unsigned short tmp[8] = {f2bf(v0.x), f2bf(v0.y), f2bf(v0.z), f2bf(v0.w),
                                     f2bf(v1.x), f2bf(v1.y), f2bf(v1.z), f2bf(v1.w)};
            *reinterpret_cast<uint4*>((char*)sA + r * 128 + ((g ^ (r & 7)) << 4)) =
                *reinterpret_cast<uint4*>(tmp);
        }
#pragma unroll
        for (int i = 0; i < 2; ++i) {
            int idx = i * 256 + t;
            int c = idx >> 3, g = idx & 7;
            uint4 v = *reinterpret_cast<const uint4*>(&W1t[(size_t)c * FIN + kb + g * 8]);
            *reinterpret_cast<uint4*>((char*)sB + c * 128 + ((g ^ (c & 7)) << 4)) = v;
        }
        __syncthreads();
#pragma unroll
        for (int ks = 0; ks < 2; ++ks) {
            const int gk = ks * 4 + (l >> 4);
            bf16x8 a[2], b[4];
#pragma unroll
            for (int fr = 0; fr < 2; ++fr) {
                int r = w * 32 + fr * 16 + (l & 15);
                a[fr] = *reinterpret_cast<const bf16x8*>((char*)sA + r * 128 + ((gk ^ (r & 7)) << 4));
            }
#pragma unroll
            for (int fc = 0; fc < 4; ++fc) {
                int c = fc * 16 + (l & 15);
                b[fc] = *reinterpret_cast<const bf16x8*>((char*)sB + c * 128 + ((gk ^ (c & 7)) << 4));
            }
#pragma unroll
            for (int fr = 0; fr < 2; ++fr)
#pragma unroll
                for (int fc = 0; fc < 4; ++fc)
                    acc[fr][fc] = __builtin_amdgcn_mfma_f32_16x16x32_bf16(
                        a[fr], b[fc], acc[fr][fc], 0, 0, 0);
        }
    }
#pragma unroll
    for (int fr = 0; fr < 2; ++fr) {
#pragma unroll
        for (int r = 0; r < 4; ++r) {
            int grow = row0 + w * 32 + fr * 16 + (l >> 4) * 4 + r;
            if (grow >= NN) continue;
            float di = dinv[grow];
#pragma unroll
            for (int fc = 0; fc < 4; ++fc) {
                int col = fc * 16 + (l & 15);
                h1s[(size_t)grow * HID + col] = f2bf(acc[fr][fc][r] * di);
            }
        }
    }
}

// ---------------- fused layer-1 aggregation + layer-2 GEMM ----------------
// per node: agg = h1s[self] + sum_nbr h1s[src] ; x = relu(agg*dinv + b1) [fp32, in regs]
// h2s[node,:] = bf16( (x @ W2) * dinv[node] )
__global__ __launch_bounds__(256) void k_agg1f(
    const unsigned* __restrict__ cnt, const int* __restrict__ ell,
    const unsigned short* __restrict__ h1s, const float* __restrict__ dinv,
    const float* __restrict__ b1, const float* __restrict__ W2,
    unsigned short* __restrict__ h2s) {
    __shared__ float sW2[HID][NC + 1];   // +1 pad: avoid 8-way conflicts on column reads
    __shared__ float sb1[HID];
    const int t = threadIdx.x;
#pragma unroll
    for (int i = 0; i < 4; ++i) {
        int idx = i * 256 + t;
        sW2[idx >> 4][idx & 15] = W2[idx];
    }
    if (t < HID) sb1[t] = b1[t];
    __syncthreads();

    int wid = (blockIdx.x * blockDim.x + t) >> 6;
    if (wid >= NN) return;
    const int l = t & 63;
    const int g = l >> 3;      // edge subgroup 0..7 (also: output column pair 2g,2g+1)
    const int q = l & 7;       // channel octet: channels q*8 .. q*8+7
    const int total = (int)cnt[wid] + 1;   // +1 virtual self edge (e==0)
    const int base = wid * ELLW;

    float a0 = 0.f, a1 = 0.f, a2 = 0.f, a3 = 0.f;
    float a4 = 0.f, a5 = 0.f, a6 = 0.f, a7 = 0.f;
    for (int s = 0; s < total; s += 8) {
        int e = s + g;
        int ee = min(e, total - 1);
        int src = (ee == 0) ? wid : ell[base + ee - 1];
        uint4 u = *reinterpret_cast<const uint4*>(&h1s[(size_t)src * HID + q * 8]);
        float m = (e < total) ? 1.f : 0.f;
        a0 = fmaf(m, asf(u.x << 16), a0);
        a1 = fmaf(m, asf(u.x & 0xFFFF0000u), a1);
        a2 = fmaf(m, asf(u.y << 16), a2);
        a3 = fmaf(m, asf(u.y & 0xFFFF0000u), a3);
        a4 = fmaf(m, asf(u.z << 16), a4);
        a5 = fmaf(m, asf(u.z & 0xFFFF0000u), a5);
        a6 = fmaf(m, asf(u.w << 16), a6);
        a7 = fmaf(m, asf(u.w & 0xFFFF0000u), a7);
    }
#pragma unroll
    for (int d = 8; d <= 32; d <<= 1) {
        a0 += __shfl_xor(a0, d); a1 += __shfl_xor(a1, d);
        a2 += __shfl_xor(a2, d); a3 += __shfl_xor(a3, d);
        a4 += __shfl_xor(a4, d); a5 += __shfl_xor(a5, d);
        a6 += __shfl_xor(a6, d); a7 += __shfl_xor(a7, d);
    }
    // all 64 lanes now hold the full sums for channels q*8..q*8+7
    const float di = dinv[wid];
    const int ch0 = q * 8;
    float x0 = fmaxf(fmaf(a0, di, sb1[ch0 + 0]), 0.f);
    float x1 = fmaxf(fmaf(a1, di, sb1[ch0 + 1]), 0.f);
    float x2 = fmaxf(fmaf(a2, di, sb1[ch0 + 2]), 0.f);
    float x3 = fmaxf(fmaf(a3, di, sb1[ch0 + 3]), 0.f);
    float x4 = fmaxf(fmaf(a4, di, sb1[ch0 + 4]), 0.f);
    float x5 = fmaxf(fmaf(a5, di, sb1[ch0 + 5]), 0.f);
    float x6 = fmaxf(fmaf(a6, di, sb1[ch0 + 6]), 0.f);
    float x7 = fmaxf(fmaf(a7, di, sb1[ch0 + 7]), 0.f);
    // partials for output columns 2g, 2g+1 over this lane's 8 channels
    const int c0 = 2 * g, c1 = 2 * g + 1;
    float p0 = x0 * sW2[ch0 + 0][c0] + x1 * sW2[ch0 + 1][c0] + x2 * sW2[ch0 + 2][c0] +
               x3 * sW2[ch0 + 3][c0] + x4 * sW2[ch0 + 4][c0] + x5 * sW2[ch0 + 5][c0] +
               x6 * sW2[ch0 + 6][c0] + x7 * sW2[ch0 + 7][c0];
    float p1 = x0 * sW2[ch0 + 0][c1] + x1 * sW2[ch0 + 1][c1] + x2 * sW2[ch0 + 2][c1] +
               x3 * sW2[ch0 + 3][c1] + x4 * sW2[ch0 + 4][c1] + x5 * sW2[ch0 + 5][c1] +
               x6 * sW2[ch0 + 6][c1] + x7 * sW2[ch0 + 7][c1];
    // reduce across the 8 channel-octet lanes (q dimension: xor 1,2,4)
    p0 += __shfl_xor(p0, 1); p1 += __shfl_xor(p1, 1);
    p0 += __shfl_xor(p0, 2); p1 += __shfl_xor(p1, 2);
    p0 += __shfl_xor(p0, 4); p1 += __shfl_xor(p1, 4);
    if (q == 0) {
        unsigned u = (unsigned)f2bf(p0 * di) | ((unsigned)f2bf(p1 * di) << 16);
        *reinterpret_cast<unsigned*>(&h2s[(size_t)wid * NC + c0]) = u;
    }
}

// ---------------- layer 2 aggregation: wave/node, 32 edges/iter, 8ch/lane ----------------
__global__ __launch_bounds__(256) void k_agg2(
    const unsigned* __restrict__ cnt, const int* __restrict__ ell,
    const unsigned short* __restrict__ h2s, const float* __restrict__ dinv,
    const float* __restrict__ b2, float* __restrict__ out) {
    int wid = (blockIdx.x * blockDim.x + threadIdx.x) >> 6;
    if (wid >= NN) return;
    const int l = threadIdx.x & 63;
    const int g = l >> 1;      // edge subgroup 0..31
    const int q = l & 1;       // channel octet
    const int total = (int)cnt[wid] + 1;   // +1 self
    const int base = wid * ELLW;

    float a0 = 0.f, a1 = 0.f, a2 = 0.f, a3 = 0.f;
    float a4 = 0.f, a5 = 0.f, a6 = 0.f, a7 = 0.f;
    for (int s = 0; s < total; s += 32) {
        int e = s + g;
        int ee = min(e, total - 1);
        int src = (ee == 0) ? wid : ell[base + ee - 1];
        uint4 u = *reinterpret_cast<const uint4*>(&h2s[(size_t)src * NC + q * 8]);
        float m = (e < total) ? 1.f : 0.f;
        a0 = fmaf(m, asf(u.x << 16), a0);
        a1 = fmaf(m, asf(u.x & 0xFFFF0000u), a1);
        a2 = fmaf(m, asf(u.y << 16), a2);
        a3 = fmaf(m, asf(u.y & 0xFFFF0000u), a3);
        a4 = fmaf(m, asf(u.z << 16), a4);
        a5 = fmaf(m, asf(u.z & 0xFFFF0000u), a5);
        a6 = fmaf(m, asf(u.w << 16), a6);
        a7 = fmaf(m, asf(u.w & 0xFFFF0000u), a7);
    }
#pragma unroll
    for (int d = 2; d <= 32; d <<= 1) {
        a0 += __shfl_xor(a0, d); a1 += __shfl_xor(a1, d);
        a2 += __shfl_xor(a2, d); a3 += __shfl_xor(a3, d);
        a4 += __shfl_xor(a4, d); a5 += __shfl_xor(a5, d);
        a6 += __shfl_xor(a6, d); a7 += __shfl_xor(a7, d);
    }
    if (g == 0) {   // lanes 0,1
        float di = dinv[wid];
        float4 bA = *reinterpret_cast<const float4*>(&b2[q * 8]);
        float4 bB = *reinterpret_cast<const float4*>(&b2[q * 8 + 4]);
        float4 w0, w1;
        w0.x = fmaf(a0, di, bA.x); w0.y = fmaf(a1, di, bA.y);
        w0.z = fmaf(a2, di, bA.z); w0.w = fmaf(a3, di, bA.w);
        w1.x = fmaf(a4, di, bB.x); w1.y = fmaf(a5, di, bB.y);
        w1.z = fmaf(a6, di, bB.z); w1.w = fmaf(a7, di, bB.w);
        *reinterpret_cast<float4*>(&out[(size_t)wid * NC + q * 8])     = w0;
        *reinterpret_cast<float4*>(&out[(size_t)wid * NC + q * 8 + 4]) = w1;
    }
}

extern "C" void kernel_launch(void* const* d_in, const int* in_sizes, int n_in,
                              void* d_out, int out_size, void* d_ws, size_t ws_size,
                              hipStream_t stream) {
    const float* features = (const float*)d_in[0];
    const int*   edges    = (const int*)d_in[1];   // [2, E] int32
    const float* W1       = (const float*)d_in[2];
    const float* b1       = (const float*)d_in[3];
    const float* W2       = (const float*)d_in[4];
    const float* b2       = (const float*)d_in[5];
    float* out = (float*)d_out;

    const int* erow = edges;        // sources
    const int* ecol = edges + EE;   // targets

    // ---- workspace layout ----
    char* ws = (char*)d_ws;
    size_t o = 0;
    auto alloc = [&](size_t bytes) { size_t p = o; o = (o + bytes + 255) & ~255ULL; return p; };
    unsigned*       gcur  = (unsigned*)      (ws + alloc((size_t)KB2 * CPAD * 4));         // 25 KB
    unsigned*       cnt   = (unsigned*)      (ws + alloc((size_t)NN * 4));
    float*          dinv  = (float*)         (ws + alloc((size_t)NN * 4));
    unsigned*       staged= (unsigned*)      (ws + alloc((size_t)KB2 * BCAP2 * 4));        // 7.2 MB
    unsigned short* W1t   = (unsigned short*)(ws + alloc((size_t)HID * FIN * 2));
    int*            ell   = (int*)           (ws + alloc((size_t)(KB2 << 8) * ELLW * 4));  // 25.6 MB
    unsigned short* h1s   = (unsigned short*)(ws + alloc((size_t)NN * HID * 2));           // bf16, dinv-prefolded
    unsigned short* h2s   = (unsigned short*)(ws + alloc((size_t)NN * NC * 2));            // bf16, dinv-prefolded

    // ---- 6-dispatch pipeline ----
    k_init <<<128, 256, 0, stream>>>(W1, W1t, gcur);
    k_bin  <<<(EE + S1E - 1) / S1E, 256, 0, stream>>>(erow, ecol, gcur, staged);
    k_scat2<<<KB2, 256, 0, stream>>>(gcur, staged, ell, cnt, dinv);
    k_gemm1<<<(NN + BM - 1) / BM, 256, 0, stream>>>(features, W1t, dinv, h1s);
    k_agg1f<<<NN / 4, 256, 0, stream>>>(cnt, ell, h1s, dinv, b1, W2, h2s);
    k_agg2 <<<NN / 4, 256, 0, stream>>>(cnt, ell, h2s, dinv, b2, out);
}

// Round 9
// 193.789 us; speedup vs baseline: 1.0507x; 1.0507x over previous
//
#include <hip/hip_runtime.h>

#define NN 100000
#define EE 1600000
#define FIN 512
#define HID 64
#define NC 16
#define ELLW 64          // max in-degree capacity (Poisson(16), max ~42)
#define CPAD 16          // one bucket cursor per 64B line

#define KB2 391          // buckets: 256 dst nodes each, ceil(100000/256)
#define BCAP2 4608       // staged entries per bucket (mean 4096, +8 sigma)
#define S1E 2048         // edges per bin block

typedef __attribute__((ext_vector_type(8))) short bf16x8;
typedef __attribute__((ext_vector_type(4))) float f32x4;

__device__ __forceinline__ unsigned short f2bf(float f) {
    union { float f; unsigned u; } v; v.f = f;
    unsigned r = v.u + 0x7FFFu + ((v.u >> 16) & 1u);   // RNE
    return (unsigned short)(r >> 16);
}
__device__ __forceinline__ float asf(unsigned u) {
    union { unsigned u; float f; } v; v.u = u; return v.f;
}

// ---------------- init: zero bucket cursors + W1 -> bf16 transposed [col][k] ----------------
__global__ void k_init(const float* __restrict__ W1, unsigned short* __restrict__ W1t,
                       unsigned* __restrict__ gcur) {
    int id = blockIdx.x * blockDim.x + threadIdx.x;
    if (id < KB2 * CPAD) gcur[id] = 0u;
    if (id < HID * FIN) {
        int c = id >> 9;      // col 0..63
        int k = id & 511;
        W1t[id] = f2bf(W1[(size_t)k * HID + c]);
    }
}

// ---------------- bin: bucket edges by dst (256-node buckets), coalesced staged output ----------------
__global__ __launch_bounds__(256) void k_bin(
    const int* __restrict__ erow, const int* __restrict__ ecol,
    unsigned* __restrict__ gcur, unsigned* __restrict__ staged) {
    __shared__ unsigned hist[512];
    __shared__ unsigned scanb[512];
    __shared__ unsigned cur[512];
    __shared__ unsigned sbase[512];
    __shared__ unsigned pk[S1E];
    __shared__ unsigned ga[S1E];
    const int t = threadIdx.x;
    const int e0 = blockIdx.x * S1E;

    hist[t] = 0; hist[t + 256] = 0;
    cur[t] = 0;  cur[t + 256] = 0;
    __syncthreads();

    unsigned pkd[8];
    int bs[8];
#pragma unroll
    for (int i = 0; i < 8; ++i) {
        int e = e0 + i * 256 + t;
        if (e < EE) {
            int c = ecol[e];
            int src = erow[e];
            int b = c >> 8;                       // 0..390
            bs[i] = b;
            pkd[i] = (unsigned)src | ((unsigned)(c & 255) << 17);
            atomicAdd(&hist[b], 1u);
        } else {
            bs[i] = -1;
        }
    }
    __syncthreads();
    // two parallel 256-wide inclusive scans, then offset the upper half
    scanb[t] = hist[t];
    scanb[t + 256] = hist[t + 256];
    __syncthreads();
    for (int d = 1; d < 256; d <<= 1) {
        unsigned aA = (t >= d) ? scanb[t - d] : 0u;
        unsigned aB = (t >= d) ? scanb[256 + t - d] : 0u;
        __syncthreads();
        scanb[t] += aA;
        scanb[256 + t] += aB;
        __syncthreads();
    }
    unsigned totA = scanb[255];
    scanb[256 + t] += totA;
    __syncthreads();
    // reserve global ranges per bucket
    if (hist[t] > 0) sbase[t] = atomicAdd(&gcur[(size_t)t * CPAD], hist[t]);
    {
        int t2 = t + 256;
        if (t2 < KB2 && hist[t2] > 0) sbase[t2] = atomicAdd(&gcur[(size_t)t2 * CPAD], hist[t2]);
    }
    __syncthreads();
#pragma unroll
    for (int i = 0; i < 8; ++i) {
        int b = bs[i];
        if (b >= 0) {
            unsigned ls = atomicAdd(&cur[b], 1u);
            unsigned pos = scanb[b] - hist[b] + ls;
            unsigned gp = sbase[b] + ls;
            pk[pos] = pkd[i];
            ga[pos] = (gp < BCAP2) ? ((unsigned)b * BCAP2 + gp) : 0xFFFFFFFFu;
        }
    }
    __syncthreads();
    unsigned tot = scanb[511];
#pragma unroll
    for (int i = 0; i < 8; ++i) {
        unsigned idx = i * 256 + t;
        if (idx < tot && ga[idx] != 0xFFFFFFFFu) staged[ga[idx]] = pk[idx];
    }
}

// ---------------- scat2: LDS-resident ELL tile, coalesced write-out ----------------
// 2 blocks per bucket; block handles 128 nodes. tile stride 65 spreads LDS banks by row.
__global__ __launch_bounds__(256) void k_scat2(
    const unsigned* __restrict__ gcur, const unsigned* __restrict__ staged,
    int* __restrict__ ell, unsigned* __restrict__ cnt, float* __restrict__ dinv) {
    __shared__ int tile[128 * 65];     // 33.3 KB
    __shared__ unsigned lcnt[128];
    const int t = threadIdx.x;
    const int b = blockIdx.x >> 1;     // bucket
    const int dl0 = (blockIdx.x & 1) << 7;   // node offset within bucket: 0 or 128
    if (t < 128) lcnt[t] = 0;
    __syncthreads();
    unsigned n = gcur[(size_t)b * CPAD];
    if (n > BCAP2) n = BCAP2;
    const unsigned base = (unsigned)b * BCAP2;
    for (unsigned idx = t; idx < n; idx += 256) {
        unsigned p = staged[base + idx];
        int dl = (int)(p >> 17) - dl0;
        if ((unsigned)dl < 128u) {
            int src = (int)(p & 0x1FFFFu);
            unsigned slot = atomicAdd(&lcnt[dl], 1u);
            if (slot < ELLW) tile[dl * 65 + slot] = src;   // bank = (dl+slot)&31
        }
    }
    __syncthreads();
    const int node0 = (b << 8) + dl0;
    int nrows = NN - node0;
    if (nrows > 128) nrows = 128;
    if (nrows > 0) {
        // coalesced write-out: consecutive lanes -> consecutive global dwords
        int* eout = ell + (size_t)node0 * ELLW;
        for (int i = t; i < nrows * ELLW; i += 256) {
            int row = i >> 6, col = i & 63;
            eout[i] = tile[row * 65 + col];
        }
        if (t < nrows) {
            int node = node0 + t;
            unsigned c = lcnt[t];
            cnt[node] = c;
            dinv[node] = 1.0f / sqrtf((float)(c + 1u));   // +1 self-loop
        }
    }
}

// ---------------- layer 1 GEMM via MFMA: h1s = bf16( (A@W1) * dinv ) ----------------
#define BM 128
#define BK 64

__global__ __launch_bounds__(256) void k_gemm1(
    const float* __restrict__ A, const unsigned short* __restrict__ W1t,
    const float* __restrict__ dinv, unsigned short* __restrict__ h1s) {
    __shared__ unsigned short sA[BM * BK];   // 16 KB
    __shared__ unsigned short sB[HID * BK];  // 8 KB
    const int t = threadIdx.x;
    const int w = t >> 6;
    const int l = t & 63;
    const int row0 = blockIdx.x * BM;

    f32x4 acc[2][4];
#pragma unroll
    for (int fr = 0; fr < 2; ++fr)
#pragma unroll
        for (int fc = 0; fc < 4; ++fc)
            acc[fr][fc] = (f32x4){0.f, 0.f, 0.f, 0.f};

    for (int kb = 0; kb < FIN; kb += BK) {
        __syncthreads();
#pragma unroll
        for (int i = 0; i < 4; ++i) {
            int idx = i * 256 + t;
            int r = idx >> 3, g = idx & 7;
            float4 v0 = {0.f, 0.f, 0.f, 0.f}, v1 = {0.f, 0.f, 0.f, 0.f};
            if (row0 + r < NN) {
                const float* p = &A[(size_t)(row0 + r) * FIN + kb + g * 8];
                v0 = *reinterpret_cast<const float4*>(p);
                v1 = *reinterpret_cast<const float4*>(p + 4);
            }
            unsigned short tmp[8] = {f2bf(v0.x), f2bf(v0.y), f2bf(v0.z), f2bf(v0.w),
                                     f2bf(v1.x), f2bf(v1.y), f2bf(v1.z), f2bf(v1.w)};
            *reinterpret_cast<uint4*>((char*)sA + r * 128 + ((g ^ (r & 7)) << 4)) =
                *reinterpret_cast<uint4*>(tmp);
        }
#pragma unroll
        for (int i = 0; i < 2; ++i) {
            int idx = i * 256 + t;
            int c = idx >> 3, g = idx & 7;
            uint4 v = *reinterpret_cast<const uint4*>(&W1t[(size_t)c * FIN + kb + g * 8]);
            *reinterpret_cast<uint4*>((char*)sB + c * 128 + ((g ^ (c & 7)) << 4)) = v;
        }
        __syncthreads();
#pragma unroll
        for (int ks = 0; ks < 2; ++ks) {
            const int gk = ks * 4 + (l >> 4);
            bf16x8 a[2], b[4];
#pragma unroll
            for (int fr = 0; fr < 2; ++fr) {
                int r = w * 32 + fr * 16 + (l & 15);
                a[fr] = *reinterpret_cast<const bf16x8*>((char*)sA + r * 128 + ((gk ^ (r & 7)) << 4));
            }
#pragma unroll
            for (int fc = 0; fc < 4; ++fc) {
                int c = fc * 16 + (l & 15);
                b[fc] = *reinterpret_cast<const bf16x8*>((char*)sB + c * 128 + ((gk ^ (c & 7)) << 4));
            }
#pragma unroll
            for (int fr = 0; fr < 2; ++fr)
#pragma unroll
                for (int fc = 0; fc < 4; ++fc)
                    acc[fr][fc] = __builtin_amdgcn_mfma_f32_16x16x32_bf16(
                        a[fr], b[fc], acc[fr][fc], 0, 0, 0);
        }
    }
#pragma unroll
    for (int fr = 0; fr < 2; ++fr) {
#pragma unroll
        for (int r = 0; r < 4; ++r) {
            int grow = row0 + w * 32 + fr * 16 + (l >> 4) * 4 + r;
            if (grow >= NN) continue;
            float di = dinv[grow];
#pragma unroll
            for (int fc = 0; fc < 4; ++fc) {
                int col = fc * 16 + (l & 15);
                h1s[(size_t)grow * HID + col] = f2bf(acc[fr][fc][r] * di);
            }
        }
    }
}

// ---------------- layer 1 aggregation: wave/node, 8 edges/iter, 8ch/lane ----------------
__global__ __launch_bounds__(256) void k_agg1(
    const unsigned* __restrict__ cnt, const int* __restrict__ ell,
    const unsigned short* __restrict__ h1s, const float* __restrict__ dinv,
    const float* __restrict__ b1, unsigned short* __restrict__ x) {
    int wid = (blockIdx.x * blockDim.x + threadIdx.x) >> 6;
    if (wid >= NN) return;
    const int l = threadIdx.x & 63;
    const int g = l >> 3;      // edge subgroup 0..7
    const int q = l & 7;       // channel octet
    const int total = (int)cnt[wid] + 1;   // +1 virtual self edge (e==0)
    const int base = wid * ELLW;

    float a0 = 0.f, a1 = 0.f, a2 = 0.f, a3 = 0.f;
    float a4 = 0.f, a5 = 0.f, a6 = 0.f, a7 = 0.f;
    for (int s = 0; s < total; s += 8) {
        int e = s + g;
        int ee = min(e, total - 1);
        int src = (ee == 0) ? wid : ell[base + ee - 1];
        uint4 u = *reinterpret_cast<const uint4*>(&h1s[(size_t)src * HID + q * 8]);
        float m = (e < total) ? 1.f : 0.f;
        a0 = fmaf(m, asf(u.x << 16), a0);
        a1 = fmaf(m, asf(u.x & 0xFFFF0000u), a1);
        a2 = fmaf(m, asf(u.y << 16), a2);
        a3 = fmaf(m, asf(u.y & 0xFFFF0000u), a3);
        a4 = fmaf(m, asf(u.z << 16), a4);
        a5 = fmaf(m, asf(u.z & 0xFFFF0000u), a5);
        a6 = fmaf(m, asf(u.w << 16), a6);
        a7 = fmaf(m, asf(u.w & 0xFFFF0000u), a7);
    }
#pragma unroll
    for (int d = 8; d <= 32; d <<= 1) {
        a0 += __shfl_xor(a0, d); a1 += __shfl_xor(a1, d);
        a2 += __shfl_xor(a2, d); a3 += __shfl_xor(a3, d);
        a4 += __shfl_xor(a4, d); a5 += __shfl_xor(a5, d);
        a6 += __shfl_xor(a6, d); a7 += __shfl_xor(a7, d);
    }
    if (g == 0) {
        float di = dinv[wid];
        float4 bA = *reinterpret_cast<const float4*>(&b1[q * 8]);
        float4 bB = *reinterpret_cast<const float4*>(&b1[q * 8 + 4]);
        float r0 = fmaxf(fmaf(a0, di, bA.x), 0.f);
        float r1 = fmaxf(fmaf(a1, di, bA.y), 0.f);
        float r2 = fmaxf(fmaf(a2, di, bA.z), 0.f);
        float r3 = fmaxf(fmaf(a3, di, bA.w), 0.f);
        float r4 = fmaxf(fmaf(a4, di, bB.x), 0.f);
        float r5 = fmaxf(fmaf(a5, di, bB.y), 0.f);
        float r6 = fmaxf(fmaf(a6, di, bB.z), 0.f);
        float r7 = fmaxf(fmaf(a7, di, bB.w), 0.f);
        uint4 pv;
        pv.x = (unsigned)f2bf(r0) | ((unsigned)f2bf(r1) << 16);
        pv.y = (unsigned)f2bf(r2) | ((unsigned)f2bf(r3) << 16);
        pv.z = (unsigned)f2bf(r4) | ((unsigned)f2bf(r5) << 16);
        pv.w = (unsigned)f2bf(r6) | ((unsigned)f2bf(r7) << 16);
        *reinterpret_cast<uint4*>(&x[(size_t)wid * HID + q * 8]) = pv;
    }
}

// ---------------- layer 2 GEMM: h2s = bf16( (x @ W2) * dinv ), x bf16 ----------------
__global__ __launch_bounds__(256) void k_gemm2(
    const unsigned short* __restrict__ x, const float* __restrict__ W2,
    const float* __restrict__ dinv, unsigned short* __restrict__ h2s) {
    __shared__ float sW[HID][NC];   // 4 KB
    const int t = threadIdx.x;
#pragma unroll
    for (int i = 0; i < 4; ++i) {
        int q = t + i * 256;
        sW[q >> 4][q & 15] = W2[q];
    }
    __syncthreads();
    int i = blockIdx.x * blockDim.x + t;
    if (i >= NN) return;

    float acc[NC];
#pragma unroll
    for (int j = 0; j < NC; ++j) acc[j] = 0.f;
    const unsigned short* xr = &x[(size_t)i * HID];
#pragma unroll
    for (int k8 = 0; k8 < 8; ++k8) {
        uint4 u = *reinterpret_cast<const uint4*>(&xr[k8 * 8]);
        float f[8] = {asf(u.x << 16), asf(u.x & 0xFFFF0000u),
                      asf(u.y << 16), asf(u.y & 0xFFFF0000u),
                      asf(u.z << 16), asf(u.z & 0xFFFF0000u),
                      asf(u.w << 16), asf(u.w & 0xFFFF0000u)};
#pragma unroll
        for (int m = 0; m < 8; ++m)
#pragma unroll
            for (int j = 0; j < NC; ++j)
                acc[j] = fmaf(f[m], sW[k8 * 8 + m][j], acc[j]);
    }
    float di = dinv[i];
    unsigned short hv[NC];
#pragma unroll
    for (int j = 0; j < NC; ++j) hv[j] = f2bf(acc[j] * di);
    *reinterpret_cast<uint4*>(&h2s[(size_t)i * NC])     = *reinterpret_cast<uint4*>(hv);
    *reinterpret_cast<uint4*>(&h2s[(size_t)i * NC + 8]) = *reinterpret_cast<uint4*>(hv + 8);
}

// ---------------- layer 2 aggregation: wave/node, 32 edges/iter, 8ch/lane ----------------
__global__ __launch_bounds__(256) void k_agg2(
    const unsigned* __restrict__ cnt, const int* __restrict__ ell,
    const unsigned short* __restrict__ h2s, const float* __restrict__ dinv,
    const float* __restrict__ b2, float* __restrict__ out) {
    int wid = (blockIdx.x * blockDim.x + threadIdx.x) >> 6;
    if (wid >= NN) return;
    const int l = threadIdx.x & 63;
    const int g = l >> 1;      // edge subgroup 0..31
    const int q = l & 1;       // channel octet
    const int total = (int)cnt[wid] + 1;   // +1 self
    const int base = wid * ELLW;

    float a0 = 0.f, a1 = 0.f, a2 = 0.f, a3 = 0.f;
    float a4 = 0.f, a5 = 0.f, a6 = 0.f, a7 = 0.f;
    for (int s = 0; s < total; s += 32) {
        int e = s + g;
        int ee = min(e, total - 1);
        int src = (ee == 0) ? wid : ell[base + ee - 1];
        uint4 u = *reinterpret_cast<const uint4*>(&h2s[(size_t)src * NC + q * 8]);
        float m = (e < total) ? 1.f : 0.f;
        a0 = fmaf(m, asf(u.x << 16), a0);
        a1 = fmaf(m, asf(u.x & 0xFFFF0000u), a1);
        a2 = fmaf(m, asf(u.y << 16), a2);
        a3 = fmaf(m, asf(u.y & 0xFFFF0000u), a3);
        a4 = fmaf(m, asf(u.z << 16), a4);
        a5 = fmaf(m, asf(u.z & 0xFFFF0000u), a5);
        a6 = fmaf(m, asf(u.w << 16), a6);
        a7 = fmaf(m, asf(u.w & 0xFFFF0000u), a7);
    }
#pragma unroll
    for (int d = 2; d <= 32; d <<= 1) {
        a0 += __shfl_xor(a0, d); a1 += __shfl_xor(a1, d);
        a2 += __shfl_xor(a2, d); a3 += __shfl_xor(a3, d);
        a4 += __shfl_xor(a4, d); a5 += __shfl_xor(a5, d);
        a6 += __shfl_xor(a6, d); a7 += __shfl_xor(a7, d);
    }
    if (g == 0) {   // lanes 0,1
        float di = dinv[wid];
        float4 bA = *reinterpret_cast<const float4*>(&b2[q * 8]);
        float4 bB = *reinterpret_cast<const float4*>(&b2[q * 8 + 4]);
        float4 w0, w1;
        w0.x = fmaf(a0, di, bA.x); w0.y = fmaf(a1, di, bA.y);
        w0.z = fmaf(a2, di, bA.z); w0.w = fmaf(a3, di, bA.w);
        w1.x = fmaf(a4, di, bB.x); w1.y = fmaf(a5, di, bB.y);
        w1.z = fmaf(a6, di, bB.z); w1.w = fmaf(a7, di, bB.w);
        *reinterpret_cast<float4*>(&out[(size_t)wid * NC + q * 8])     = w0;
        *reinterpret_cast<float4*>(&out[(size_t)wid * NC + q * 8 + 4]) = w1;
    }
}

extern "C" void kernel_launch(void* const* d_in, const int* in_sizes, int n_in,
                              void* d_out, int out_size, void* d_ws, size_t ws_size,
                              hipStream_t stream) {
    const float* features = (const float*)d_in[0];
    const int*   edges    = (const int*)d_in[1];   // [2, E] int32
    const float* W1       = (const float*)d_in[2];
    const float* b1       = (const float*)d_in[3];
    const float* W2       = (const float*)d_in[4];
    const float* b2       = (const float*)d_in[5];
    float* out = (float*)d_out;

    const int* erow = edges;        // sources
    const int* ecol = edges + EE;   // targets

    // ---- workspace layout ----
    char* ws = (char*)d_ws;
    size_t o = 0;
    auto alloc = [&](size_t bytes) { size_t p = o; o = (o + bytes + 255) & ~255ULL; return p; };
    unsigned*       gcur  = (unsigned*)      (ws + alloc((size_t)KB2 * CPAD * 4));         // 25 KB
    unsigned*       cnt   = (unsigned*)      (ws + alloc((size_t)NN * 4));
    float*          dinv  = (float*)         (ws + alloc((size_t)NN * 4));
    unsigned*       staged= (unsigned*)      (ws + alloc((size_t)KB2 * BCAP2 * 4));        // 7.2 MB
    unsigned short* W1t   = (unsigned short*)(ws + alloc((size_t)HID * FIN * 2));
    int*            ell   = (int*)           (ws + alloc((size_t)(KB2 << 8) * ELLW * 4));  // 25.6 MB
    unsigned short* h1s   = (unsigned short*)(ws + alloc((size_t)NN * HID * 2));           // bf16, dinv-prefolded
    unsigned short* x     = (unsigned short*)(ws + alloc((size_t)NN * HID * 2));           // bf16
    unsigned short* h2s   = (unsigned short*)(ws + alloc((size_t)NN * NC * 2));            // bf16, dinv-prefolded

    // ---- 7-dispatch pipeline ----
    k_init <<<128, 256, 0, stream>>>(W1, W1t, gcur);
    k_bin  <<<(EE + S1E - 1) / S1E, 256, 0, stream>>>(erow, ecol, gcur, staged);
    k_scat2<<<KB2 * 2, 256, 0, stream>>>(gcur, staged, ell, cnt, dinv);
    k_gemm1<<<(NN + BM - 1) / BM, 256, 0, stream>>>(features, W1t, dinv, h1s);
    k_agg1 <<<NN / 4, 256, 0, stream>>>(cnt, ell, h1s, dinv, b1, x);
    k_gemm2<<<(NN + 255) / 256, 256, 0, stream>>>(x, W2, dinv, h2s);
    k_agg2 <<<NN / 4, 256, 0, stream>>>(cnt, ell, h2s, dinv, b2, out);
}